// Round 7
// baseline (910.795 us; speedup 1.0000x reference)
//
#include <hip/hip_runtime.h>
#include <math.h>

#define B_ 4
#define F_ 16
#define N_ 1024
#define V_ 4

#define ATT_BLOCKS 1024   // persistent: each owns 64 rows of one (vv,b) matrix, 8 chunks x 8 rows
#define REC_BLOCKS 256    // each handles 256 points
#define ID_BLOCKS  256    // one per (v,b,f)

typedef float vf4 __attribute__((ext_vector_type(4)));   // clang-native float4

// ---------------- workspace layout (all slots written unconditionally every launch) ----
//   double attp[1024];          offset 0       (8192 B)
//   float  recp[256*8];         offset 8192    (8192 B)   {se,c,mn0,mn1,mn2,mx0,mx1,mx2}
//   float  idp[256];            offset 16384   (1024 B)

__device__ __forceinline__ float softplusf(float x) {
    float ax = fabsf(x);
    float e = __expf(-ax);                 // exp(-|x|) in (0,1]
    return fmaxf(x, 0.0f) + __logf(1.0f + e);
}

__global__ __launch_bounds__(256) void mega_kernel(const float* __restrict__ pred,
                                                   const float* __restrict__ gt,
                                                   const int* __restrict__ vis,
                                                   const float* __restrict__ proj,
                                                   const float* __restrict__ tracks,
                                                   const float* __restrict__ corr,
                                                   double* __restrict__ attp,
                                                   float* __restrict__ recp,
                                                   float* __restrict__ idp) {
    const int blk = blockIdx.x;
    const int t = threadIdx.x;
    const int wave = t >> 6, lane = t & 63;

    if (blk < ATT_BLOCKS) {
        // ---- attention BCE, persistent block: rows [g*64, g*64+64) of matrix m ----
        const int m = blk >> 4;              // 0..63  (vv*4 + b)
        const int g = blk & 15;              // row group
        const int b = m & 3;
        const int rbase = g << 6;            // first row of this block's 64

        const vf4* mat4 = (const vf4*)corr + (size_t)m * (N_ * N_ / 4);

        // prolog: issue chunk 0's 8 loads first (nothing can stall before them)
        vf4 A[8], Bb[8];
        #pragma unroll
        for (int rr = 0; rr < 8; rr++)
            A[rr] = __builtin_nontemporal_load(mat4 + (rbase + rr) * 256 + t);

        // stage frame-0 visibility for this b (cold path only)
        __shared__ unsigned char vs[N_];
        {
            int4 v4 = ((const int4*)(vis + b * (F_ * N_)))[t];
            vs[4 * t + 0] = v4.x > 0;
            vs[4 * t + 1] = v4.y > 0;
            vs[4 * t + 2] = v4.z > 0;
            vs[4 * t + 3] = v4.w > 0;
        }
        __syncthreads();   // once per block, amortized over 8 chunks

        const int j0 = 4 * t;
        vf4 sx = {0.f, 0.f, 0.f, 0.f};       // sum of x
        vf4 st = {0.f, 0.f, 0.f, 0.f};       // sum of |x|
        vf4 pr = {1.f, 1.f, 1.f, 1.f};       // prod of (1+exp(-|x|)), 64 factors <= 2^64: fp32-safe
        float acc = 0.f;                     // band corrections

        #pragma unroll
        for (int c = 0; c < 8; c++) {
            vf4* cur = (c & 1) ? Bb : A;
            vf4* nxt = (c & 1) ? A : Bb;
            const int r0 = rbase + c * 8;
            // issue next chunk's loads BEFORE computing current: memory stays busy
            if (c < 7) {
                #pragma unroll
                for (int rr = 0; rr < 8; rr++)
                    nxt[rr] = __builtin_nontemporal_load(mat4 + (r0 + 8 + rr) * 256 + t);
            }
            // hot path: softplus sum with amortized log
            #pragma unroll
            for (int rr = 0; rr < 8; rr++) {
                vf4 x = cur[rr];
                vf4 tt;
                tt.x = fabsf(x.x); tt.y = fabsf(x.y); tt.z = fabsf(x.z); tt.w = fabsf(x.w);
                vf4 e;
                e.x = __expf(-tt.x); e.y = __expf(-tt.y); e.z = __expf(-tt.z); e.w = __expf(-tt.w);
                sx += x;
                st += tt;
                pr = pr + pr * e;             // pr *= (1+e)
            }
            // cold path: band corrections (|i-j|<=2), ~4 threads per chunk
            if (j0 >= r0 - 5 && j0 <= r0 + 9) {
                #pragma unroll
                for (int rr = 0; rr < 8; rr++) {
                    const int i = r0 + rr;
                    if (j0 < i - 5 || j0 > i + 2) continue;
                    unsigned char vi = vs[i];
                    float xs[4] = {cur[rr].x, cur[rr].y, cur[rr].z, cur[rr].w};
                    #pragma unroll
                    for (int kk = 0; kk < 4; kk++) {
                        int j = j0 + kk;
                        int dd = (i > j) ? (i - j) : (j - i);
                        if (dd <= 2) {
                            if (vi | vs[j]) {
                                float gq = (dd == 0) ? 1.0f : ((dd == 1) ? 0.7f : 0.49f);
                                float sp = softplusf(xs[kk]);
                                acc += 2.f * gq * sp - (1.f + 2.f * gq) * xs[kk] * gq;
                            }
                        }
                    }
                }
            }
        }

        acc += 0.5f * ((sx.x + sx.y + sx.z + sx.w) + (st.x + st.y + st.z + st.w))
             + (__logf(pr.x) + __logf(pr.y)) + (__logf(pr.z) + __logf(pr.w));

        #pragma unroll
        for (int off = 32; off; off >>= 1) acc += __shfl_down(acc, off);
        __shared__ double sw[4];
        if (lane == 0) sw[wave] = (double)acc;
        __syncthreads();
        if (t == 0) attp[blk] = (sw[0] + sw[1]) + (sw[2] + sw[3]);

    } else if (blk < ATT_BLOCKS + REC_BLOCKS) {
        // ---------------- reconstruction partials: 256 points ----------------
        const int r = blk - ATT_BLOCKS;
        const int p = r * 256 + t;
        bool mk = vis[p] > 0;
        float gx = gt[3 * p], gy = gt[3 * p + 1], gz = gt[3 * p + 2];
        float px = pred[3 * p], py = pred[3 * p + 1], pz = pred[3 * p + 2];
        float se = 0.f;
        if (mk) {
            float dx = px - gx, dy = py - gy, dz = pz - gz;
            se = dx * dx + dy * dy + dz * dz;
        }
        float mn0 = mk ? gx : 1e30f, mn1 = mk ? gy : 1e30f, mn2 = mk ? gz : 1e30f;
        float mx0 = mk ? gx : -1e30f, mx1 = mk ? gy : -1e30f, mx2 = mk ? gz : -1e30f;
        float c = mk ? 1.f : 0.f;
        #pragma unroll
        for (int off = 32; off; off >>= 1) {
            se += __shfl_down(se, off);
            c  += __shfl_down(c, off);
            mn0 = fminf(mn0, __shfl_down(mn0, off));
            mn1 = fminf(mn1, __shfl_down(mn1, off));
            mn2 = fminf(mn2, __shfl_down(mn2, off));
            mx0 = fmaxf(mx0, __shfl_down(mx0, off));
            mx1 = fmaxf(mx1, __shfl_down(mx1, off));
            mx2 = fmaxf(mx2, __shfl_down(mx2, off));
        }
        __shared__ float sh[4][8];
        if (lane == 0) {
            sh[wave][0] = se; sh[wave][1] = c;
            sh[wave][2] = mn0; sh[wave][3] = mn1; sh[wave][4] = mn2;
            sh[wave][5] = mx0; sh[wave][6] = mx1; sh[wave][7] = mx2;
        }
        __syncthreads();
        if (t == 0) {
            se = sh[0][0]; c = sh[0][1];
            mn0 = sh[0][2]; mn1 = sh[0][3]; mn2 = sh[0][4];
            mx0 = sh[0][5]; mx1 = sh[0][6]; mx2 = sh[0][7];
            for (int w = 1; w < 4; w++) {
                se += sh[w][0]; c += sh[w][1];
                mn0 = fminf(mn0, sh[w][2]); mn1 = fminf(mn1, sh[w][3]); mn2 = fminf(mn2, sh[w][4]);
                mx0 = fmaxf(mx0, sh[w][5]); mx1 = fmaxf(mx1, sh[w][6]); mx2 = fmaxf(mx2, sh[w][7]);
            }
            float* o = recp + r * 8;
            o[0] = se; o[1] = c;
            o[2] = mn0; o[3] = mn1; o[4] = mn2;
            o[5] = mx0; o[6] = mx1; o[7] = mx2;
        }

    } else {
        // ---------------- identity (reprojection) per (v,b,f) ----------------
        const int idx = blk - (ATT_BLOCKS + REC_BLOCKS);
        const int v = idx / (B_ * F_);
        const int b = (idx / F_) % B_;
        const int f = idx % F_;
        const float* P = proj + ((size_t)(v * B_ + b)) * 12;
        const float* T = tracks + ((size_t)((v * B_ + b) * F_ + f)) * N_ * 2;
        const float* Q = pred + ((size_t)(b * F_ + f)) * N_ * 3;

        float mnx = 1e30f, mny = 1e30f, mxx = -1e30f, mxy = -1e30f;
        for (int n = t; n < N_; n += 256) {
            float tx = T[2 * n], ty = T[2 * n + 1];
            if ((fabsf(tx) + fabsf(ty)) > 1e-6f) {
                mnx = fminf(mnx, tx); mxx = fmaxf(mxx, tx);
                mny = fminf(mny, ty); mxy = fmaxf(mxy, ty);
            }
        }
        #pragma unroll
        for (int off = 32; off; off >>= 1) {
            mnx = fminf(mnx, __shfl_down(mnx, off));
            mxx = fmaxf(mxx, __shfl_down(mxx, off));
            mny = fminf(mny, __shfl_down(mny, off));
            mxy = fmaxf(mxy, __shfl_down(mxy, off));
        }
        __shared__ float shi[4][4];
        __shared__ float wh[2];
        if (lane == 0) { shi[wave][0] = mnx; shi[wave][1] = mxx; shi[wave][2] = mny; shi[wave][3] = mxy; }
        __syncthreads();
        if (t == 0) {
            float a = shi[0][0], bb = shi[0][1], c = shi[0][2], d = shi[0][3];
            for (int w = 1; w < 4; w++) {
                a = fminf(a, shi[w][0]); bb = fmaxf(bb, shi[w][1]);
                c = fminf(c, shi[w][2]); d = fmaxf(d, shi[w][3]);
            }
            wh[0] = fmaxf(224.0f, bb - a + 1e-6f);   // no-valid case: -2e30 -> 224
            wh[1] = fmaxf(224.0f, d - c + 1e-6f);
        }
        __syncthreads();
        float whx = wh[0], why = wh[1];

        float P00 = P[0], P01 = P[1], P02 = P[2], P03 = P[3];
        float P10 = P[4], P11 = P[5], P12 = P[6], P13 = P[7];
        float P20 = P[8], P21 = P[9], P22 = P[10], P23 = P[11];

        float errsum = 0.f;
        for (int n = t; n < N_; n += 256) {
            float x = Q[3 * n], y = Q[3 * n + 1], z = Q[3 * n + 2];
            float p0 = P00 * x + P01 * y + P02 * z + P03;
            float p1 = P10 * x + P11 * y + P12 * z + P13;
            float p2 = P20 * x + P21 * y + P22 * z + P23;
            float den = p2 + 1e-10f;
            float tx = T[2 * n], ty = T[2 * n + 1];
            float ex = (p0 / den - tx) / whx;
            float ey = (p1 / den - ty) / why;
            errsum += ex * ex + ey * ey;
        }
        #pragma unroll
        for (int off = 32; off; off >>= 1) errsum += __shfl_down(errsum, off);
        __shared__ float se2[4];
        if (lane == 0) se2[wave] = errsum;
        __syncthreads();
        if (t == 0) idp[idx] = (se2[0] + se2[1] + se2[2] + se2[3]) / (float)N_;
    }
}

__global__ __launch_bounds__(256) void fin_kernel(const double* __restrict__ attp,
                                                  const float* __restrict__ recp,
                                                  const float* __restrict__ idp,
                                                  float* __restrict__ out) {
    const int t = threadIdx.x;
    const int wave = t >> 6, lane = t & 63;

    double a = 0.0;
    #pragma unroll
    for (int k = 0; k < ATT_BLOCKS / 256; k++) a += attp[k * 256 + t];
    const float* rp = recp + t * 8;
    double se = (double)rp[0];
    double c  = (double)rp[1];
    float mn0 = rp[2], mn1 = rp[3], mn2 = rp[4];
    float mx0 = rp[5], mx1 = rp[6], mx2 = rp[7];
    double id = (double)idp[t];

    #pragma unroll
    for (int off = 32; off; off >>= 1) {
        a  += __shfl_down(a, off);
        se += __shfl_down(se, off);
        c  += __shfl_down(c, off);
        id += __shfl_down(id, off);
        mn0 = fminf(mn0, __shfl_down(mn0, off));
        mn1 = fminf(mn1, __shfl_down(mn1, off));
        mn2 = fminf(mn2, __shfl_down(mn2, off));
        mx0 = fmaxf(mx0, __shfl_down(mx0, off));
        mx1 = fmaxf(mx1, __shfl_down(mx1, off));
        mx2 = fmaxf(mx2, __shfl_down(mx2, off));
    }
    __shared__ double sa[4], sse[4], sc[4], sid[4];
    __shared__ float smn[3][4], smx[3][4];
    if (lane == 0) {
        sa[wave] = a; sse[wave] = se; sc[wave] = c; sid[wave] = id;
        smn[0][wave] = mn0; smn[1][wave] = mn1; smn[2][wave] = mn2;
        smx[0][wave] = mx0; smx[1][wave] = mx1; smx[2][wave] = mx2;
    }
    __syncthreads();
    if (t == 0) {
        a = sa[0]; se = sse[0]; c = sc[0]; id = sid[0];
        mn0 = smn[0][0]; mn1 = smn[1][0]; mn2 = smn[2][0];
        mx0 = smx[0][0]; mx1 = smx[1][0]; mx2 = smx[2][0];
        for (int w = 1; w < 4; w++) {
            a += sa[w]; se += sse[w]; c += sc[w]; id += sid[w];
            mn0 = fminf(mn0, smn[0][w]); mn1 = fminf(mn1, smn[1][w]); mn2 = fminf(mn2, smn[2][w]);
            mx0 = fmaxf(mx0, smx[0][w]); mx1 = fmaxf(mx1, smx[1][w]); mx2 = fmaxf(mx2, smx[2][w]);
        }
        double num = c * 3.0;
        double mse = se / fmax(num, 1.0);
        float rng = fmaxf(mx0 - mn0, fmaxf(mx1 - mn1, mx2 - mn2));
        float scale = rng + 1e-6f;
        if (c < 0.5) scale = 1.0f;
        float rec = (float)mse / (scale * scale);
        float ident = (float)(id / (double)(V_ * B_ * F_));
        float att = (float)(a / ((double)V_ * V_ * B_ * N_ * N_));
        float total = rec + 1.0f * ident + 0.5f * att;
        out[0] = total; out[1] = rec; out[2] = ident; out[3] = att;
    }
}

extern "C" void kernel_launch(void* const* d_in, const int* in_sizes, int n_in,
                              void* d_out, int out_size, void* d_ws, size_t ws_size,
                              hipStream_t stream) {
    const float* refined = (const float*)d_in[0];   // [B,F,N,3]
    const float* gtp     = (const float*)d_in[1];   // [B,F,N,3]
    const int*   vis     = (const int*)d_in[2];     // [B,F,N]
    const float* proj    = (const float*)d_in[3];   // [V,B,3,4]
    const float* tracks  = (const float*)d_in[4];   // [V,B,F,N,2]
    const float* corr    = (const float*)d_in[5];   // [V,V,B,N,N]
    float* out = (float*)d_out;

    double* attp = (double*)d_ws;
    float*  recp = (float*)((char*)d_ws + 8192);
    float*  idp  = (float*)((char*)d_ws + 16384);

    mega_kernel<<<ATT_BLOCKS + REC_BLOCKS + ID_BLOCKS, 256, 0, stream>>>(
        refined, gtp, vis, proj, tracks, corr, attp, recp, idp);
    fin_kernel<<<1, 256, 0, stream>>>(attp, recp, idp, out);
}

// Round 8
// 352.132 us; speedup vs baseline: 2.5865x; 2.5865x over previous
//
#include <hip/hip_runtime.h>
#include <math.h>

#define B_ 4
#define F_ 16
#define N_ 1024
#define V_ 4

#define ATT_BLOCKS 4096   // each handles 16 rows x 1024 cols = 16384 floats (64 KB slab)
#define REC_BLOCKS 256    // each handles 256 points
#define ID_BLOCKS  256    // one per (v,b,f)

typedef float vf4 __attribute__((ext_vector_type(4)));   // clang-native float4

// ---------------- workspace layout (all slots written unconditionally every launch) ----
//   double attp[4096];          offset 0       (32768 B)
//   float  recp[256*8];         offset 32768   (8192 B)   {se,c,mn0,mn1,mn2,mx0,mx1,mx2}
//   float  idp[256];            offset 40960   (1024 B)
//
// NOTE (r7 lesson): do NOT introduce register double-buffer arrays here — the
// A[]/B[] chunked variant hit VGPR=256 and spilled 313 MB to scratch (619 us).
// This r4 structure (~120 VGPR, 16 loads in flight, barrier between loads and
// compute) is the measured minimum at 352.9 us.

__device__ __forceinline__ float softplusf(float x) {
    float ax = fabsf(x);
    float e = __expf(-ax);                 // exp(-|x|) in (0,1]
    return fmaxf(x, 0.0f) + __logf(1.0f + e);
}

__global__ __launch_bounds__(256) void mega_kernel(const float* __restrict__ pred,
                                                   const float* __restrict__ gt,
                                                   const int* __restrict__ vis,
                                                   const float* __restrict__ proj,
                                                   const float* __restrict__ tracks,
                                                   const float* __restrict__ corr,
                                                   double* __restrict__ attp,
                                                   float* __restrict__ recp,
                                                   float* __restrict__ idp) {
    const int blk = blockIdx.x;
    const int t = threadIdx.x;
    const int wave = t >> 6, lane = t & 63;

    if (blk < ATT_BLOCKS) {
        // ---------------- attention BCE slab: rows [row0, row0+16) of matrix (vv,b) ----
        const int b = (blk >> 6) & 3;
        const int row0 = (blk & 63) << 4;
        __shared__ unsigned char vs[N_];     // frame-0 visibility for this b
        {
            int4 v4 = ((const int4*)(vis + b * (F_ * N_)))[t];
            vs[4 * t + 0] = v4.x > 0;
            vs[4 * t + 1] = v4.y > 0;
            vs[4 * t + 2] = v4.z > 0;
            vs[4 * t + 3] = v4.w > 0;
        }

        // issue all 16 slab loads up-front: 16 independent nontemporal dwordx4 in flight
        const vf4* base4 = (const vf4*)corr + (size_t)blk * 4096;
        vf4 d[16];
        #pragma unroll
        for (int k = 0; k < 16; k++)
            d[k] = __builtin_nontemporal_load(base4 + k * 256 + t);

        __syncthreads();

        const int j0 = 4 * t;                // this thread's column group (fixed across rows)
        float acc = 0.f;
        #pragma unroll
        for (int k = 0; k < 16; k++) {
            const int i = row0 + k;
            float x0 = d[k].x, x1 = d[k].y, x2 = d[k].z, x3 = d[k].w;
            float sp0 = softplusf(x0), sp1 = softplusf(x1);
            float sp2 = softplusf(x2), sp3 = softplusf(x3);
            acc += (sp0 + sp1) + (sp2 + sp3);
            if (j0 >= i - 5 && j0 <= i + 2) {       // chunk intersects |i-j|<=2 band
                float xs[4] = {x0, x1, x2, x3};
                float sps[4] = {sp0, sp1, sp2, sp3};
                unsigned char vi = vs[i];
                #pragma unroll
                for (int kk = 0; kk < 4; kk++) {
                    int j = j0 + kk;
                    int dd = (i > j) ? (i - j) : (j - i);
                    if (dd <= 2) {
                        if (vi | vs[j]) {
                            float g = (dd == 0) ? 1.0f : ((dd == 1) ? 0.7f : 0.49f);
                            // full bce = (1+2g)*(sp - x*g); sp already added above
                            acc += 2.f * g * sps[kk] - (1.f + 2.f * g) * xs[kk] * g;
                        }
                    }
                }
            }
        }
        #pragma unroll
        for (int off = 32; off; off >>= 1) acc += __shfl_down(acc, off);
        __shared__ double sw[4];
        if (lane == 0) sw[wave] = (double)acc;
        __syncthreads();
        if (t == 0) attp[blk] = (sw[0] + sw[1]) + (sw[2] + sw[3]);

    } else if (blk < ATT_BLOCKS + REC_BLOCKS) {
        // ---------------- reconstruction partials: 256 points ----------------
        const int r = blk - ATT_BLOCKS;
        const int p = r * 256 + t;
        bool m = vis[p] > 0;
        float gx = gt[3 * p], gy = gt[3 * p + 1], gz = gt[3 * p + 2];
        float px = pred[3 * p], py = pred[3 * p + 1], pz = pred[3 * p + 2];
        float se = 0.f;
        if (m) {
            float dx = px - gx, dy = py - gy, dz = pz - gz;
            se = dx * dx + dy * dy + dz * dz;
        }
        float mn0 = m ? gx : 1e30f, mn1 = m ? gy : 1e30f, mn2 = m ? gz : 1e30f;
        float mx0 = m ? gx : -1e30f, mx1 = m ? gy : -1e30f, mx2 = m ? gz : -1e30f;
        float c = m ? 1.f : 0.f;
        #pragma unroll
        for (int off = 32; off; off >>= 1) {
            se += __shfl_down(se, off);
            c  += __shfl_down(c, off);
            mn0 = fminf(mn0, __shfl_down(mn0, off));
            mn1 = fminf(mn1, __shfl_down(mn1, off));
            mn2 = fminf(mn2, __shfl_down(mn2, off));
            mx0 = fmaxf(mx0, __shfl_down(mx0, off));
            mx1 = fmaxf(mx1, __shfl_down(mx1, off));
            mx2 = fmaxf(mx2, __shfl_down(mx2, off));
        }
        __shared__ float sh[4][8];
        if (lane == 0) {
            sh[wave][0] = se; sh[wave][1] = c;
            sh[wave][2] = mn0; sh[wave][3] = mn1; sh[wave][4] = mn2;
            sh[wave][5] = mx0; sh[wave][6] = mx1; sh[wave][7] = mx2;
        }
        __syncthreads();
        if (t == 0) {
            se = sh[0][0]; c = sh[0][1];
            mn0 = sh[0][2]; mn1 = sh[0][3]; mn2 = sh[0][4];
            mx0 = sh[0][5]; mx1 = sh[0][6]; mx2 = sh[0][7];
            for (int w = 1; w < 4; w++) {
                se += sh[w][0]; c += sh[w][1];
                mn0 = fminf(mn0, sh[w][2]); mn1 = fminf(mn1, sh[w][3]); mn2 = fminf(mn2, sh[w][4]);
                mx0 = fmaxf(mx0, sh[w][5]); mx1 = fmaxf(mx1, sh[w][6]); mx2 = fmaxf(mx2, sh[w][7]);
            }
            float* o = recp + r * 8;
            o[0] = se; o[1] = c;
            o[2] = mn0; o[3] = mn1; o[4] = mn2;
            o[5] = mx0; o[6] = mx1; o[7] = mx2;
        }

    } else {
        // ---------------- identity (reprojection) per (v,b,f) ----------------
        const int idx = blk - (ATT_BLOCKS + REC_BLOCKS);
        const int v = idx / (B_ * F_);
        const int b = (idx / F_) % B_;
        const int f = idx % F_;
        const float* P = proj + ((size_t)(v * B_ + b)) * 12;
        const float* T = tracks + ((size_t)((v * B_ + b) * F_ + f)) * N_ * 2;
        const float* Q = pred + ((size_t)(b * F_ + f)) * N_ * 3;

        float mnx = 1e30f, mny = 1e30f, mxx = -1e30f, mxy = -1e30f;
        for (int n = t; n < N_; n += 256) {
            float tx = T[2 * n], ty = T[2 * n + 1];
            if ((fabsf(tx) + fabsf(ty)) > 1e-6f) {
                mnx = fminf(mnx, tx); mxx = fmaxf(mxx, tx);
                mny = fminf(mny, ty); mxy = fmaxf(mxy, ty);
            }
        }
        #pragma unroll
        for (int off = 32; off; off >>= 1) {
            mnx = fminf(mnx, __shfl_down(mnx, off));
            mxx = fmaxf(mxx, __shfl_down(mxx, off));
            mny = fminf(mny, __shfl_down(mny, off));
            mxy = fmaxf(mxy, __shfl_down(mxy, off));
        }
        __shared__ float shi[4][4];
        __shared__ float wh[2];
        if (lane == 0) { shi[wave][0] = mnx; shi[wave][1] = mxx; shi[wave][2] = mny; shi[wave][3] = mxy; }
        __syncthreads();
        if (t == 0) {
            float a = shi[0][0], bb = shi[0][1], c = shi[0][2], d = shi[0][3];
            for (int w = 1; w < 4; w++) {
                a = fminf(a, shi[w][0]); bb = fmaxf(bb, shi[w][1]);
                c = fminf(c, shi[w][2]); d = fmaxf(d, shi[w][3]);
            }
            wh[0] = fmaxf(224.0f, bb - a + 1e-6f);   // no-valid case: -2e30 -> 224
            wh[1] = fmaxf(224.0f, d - c + 1e-6f);
        }
        __syncthreads();
        float whx = wh[0], why = wh[1];

        float P00 = P[0], P01 = P[1], P02 = P[2], P03 = P[3];
        float P10 = P[4], P11 = P[5], P12 = P[6], P13 = P[7];
        float P20 = P[8], P21 = P[9], P22 = P[10], P23 = P[11];

        float errsum = 0.f;
        for (int n = t; n < N_; n += 256) {
            float x = Q[3 * n], y = Q[3 * n + 1], z = Q[3 * n + 2];
            float p0 = P00 * x + P01 * y + P02 * z + P03;
            float p1 = P10 * x + P11 * y + P12 * z + P13;
            float p2 = P20 * x + P21 * y + P22 * z + P23;
            float den = p2 + 1e-10f;
            float tx = T[2 * n], ty = T[2 * n + 1];
            float ex = (p0 / den - tx) / whx;
            float ey = (p1 / den - ty) / why;
            errsum += ex * ex + ey * ey;
        }
        #pragma unroll
        for (int off = 32; off; off >>= 1) errsum += __shfl_down(errsum, off);
        __shared__ float se2[4];
        if (lane == 0) se2[wave] = errsum;
        __syncthreads();
        if (t == 0) idp[idx] = (se2[0] + se2[1] + se2[2] + se2[3]) / (float)N_;
    }
}

__global__ __launch_bounds__(256) void fin_kernel(const double* __restrict__ attp,
                                                  const float* __restrict__ recp,
                                                  const float* __restrict__ idp,
                                                  float* __restrict__ out) {
    const int t = threadIdx.x;
    const int wave = t >> 6, lane = t & 63;

    double a = 0.0;
    #pragma unroll
    for (int k = 0; k < ATT_BLOCKS / 256; k++) a += attp[k * 256 + t];
    const float* rp = recp + t * 8;
    double se = (double)rp[0];
    double c  = (double)rp[1];
    float mn0 = rp[2], mn1 = rp[3], mn2 = rp[4];
    float mx0 = rp[5], mx1 = rp[6], mx2 = rp[7];
    double id = (double)idp[t];

    #pragma unroll
    for (int off = 32; off; off >>= 1) {
        a  += __shfl_down(a, off);
        se += __shfl_down(se, off);
        c  += __shfl_down(c, off);
        id += __shfl_down(id, off);
        mn0 = fminf(mn0, __shfl_down(mn0, off));
        mn1 = fminf(mn1, __shfl_down(mn1, off));
        mn2 = fminf(mn2, __shfl_down(mn2, off));
        mx0 = fmaxf(mx0, __shfl_down(mx0, off));
        mx1 = fmaxf(mx1, __shfl_down(mx1, off));
        mx2 = fmaxf(mx2, __shfl_down(mx2, off));
    }
    __shared__ double sa[4], sse[4], sc[4], sid[4];
    __shared__ float smn[3][4], smx[3][4];
    if (lane == 0) {
        sa[wave] = a; sse[wave] = se; sc[wave] = c; sid[wave] = id;
        smn[0][wave] = mn0; smn[1][wave] = mn1; smn[2][wave] = mn2;
        smx[0][wave] = mx0; smx[1][wave] = mx1; smx[2][wave] = mx2;
    }
    __syncthreads();
    if (t == 0) {
        a = sa[0]; se = sse[0]; c = sc[0]; id = sid[0];
        mn0 = smn[0][0]; mn1 = smn[1][0]; mn2 = smn[2][0];
        mx0 = smx[0][0]; mx1 = smx[1][0]; mx2 = smx[2][0];
        for (int w = 1; w < 4; w++) {
            a += sa[w]; se += sse[w]; c += sc[w]; id += sid[w];
            mn0 = fminf(mn0, smn[0][w]); mn1 = fminf(mn1, smn[1][w]); mn2 = fminf(mn2, smn[2][w]);
            mx0 = fmaxf(mx0, smx[0][w]); mx1 = fmaxf(mx1, smx[1][w]); mx2 = fmaxf(mx2, smx[2][w]);
        }
        double num = c * 3.0;
        double mse = se / fmax(num, 1.0);
        float rng = fmaxf(mx0 - mn0, fmaxf(mx1 - mn1, mx2 - mn2));
        float scale = rng + 1e-6f;
        if (c < 0.5) scale = 1.0f;
        float rec = (float)mse / (scale * scale);
        float ident = (float)(id / (double)(V_ * B_ * F_));
        float att = (float)(a / ((double)V_ * V_ * B_ * N_ * N_));
        float total = rec + 1.0f * ident + 0.5f * att;
        out[0] = total; out[1] = rec; out[2] = ident; out[3] = att;
    }
}

extern "C" void kernel_launch(void* const* d_in, const int* in_sizes, int n_in,
                              void* d_out, int out_size, void* d_ws, size_t ws_size,
                              hipStream_t stream) {
    const float* refined = (const float*)d_in[0];   // [B,F,N,3]
    const float* gtp     = (const float*)d_in[1];   // [B,F,N,3]
    const int*   vis     = (const int*)d_in[2];     // [B,F,N]
    const float* proj    = (const float*)d_in[3];   // [V,B,3,4]
    const float* tracks  = (const float*)d_in[4];   // [V,B,F,N,2]
    const float* corr    = (const float*)d_in[5];   // [V,V,B,N,N]
    float* out = (float*)d_out;

    double* attp = (double*)d_ws;
    float*  recp = (float*)((char*)d_ws + 32768);
    float*  idp  = (float*)((char*)d_ws + 40960);

    mega_kernel<<<ATT_BLOCKS + REC_BLOCKS + ID_BLOCKS, 256, 0, stream>>>(
        refined, gtp, vis, proj, tracks, corr, attp, recp, idp);
    fin_kernel<<<1, 256, 0, stream>>>(attp, recp, idp, out);
}